// Round 3
// baseline (384.388 us; speedup 1.0000x reference)
//
#include <hip/hip_runtime.h>

#define NPTS 131072
#define NCEN 128
#define RROWS 24   // rgbs rows prefetched to registers (96 VGPRs), hidden under pass-1
#define NBLK (NPTS / 256)   // 512 blocks, 4 waves each -> 2048 pen slots

// Mahalanobis quadratic form, numpy-order (mul then add, explicit _rn ops: no
// fma contraction). Table stored column-major as 3 float4 per center:
//   v0 = (W[0],W[3],W[6], cx)  v1 = (W[1],W[4],W[7], cy)  v2 = (W[2],W[5],W[8], cz)
// -> exactly 3 ds_read_b128 per eval. Arithmetic order identical across both
// passes (same LDS copy) -> pass-2 recompute reproduces pass-1 selection exactly.
__device__ __forceinline__ float qeval4(float4 v0, float4 v1, float4 v2,
                                        float px, float py, float pz) {
    float dx = __fsub_rn(px, v0.w);
    float dy = __fsub_rn(py, v1.w);
    float dz = __fsub_rn(pz, v2.w);
    float t0 = __fadd_rn(__fadd_rn(__fmul_rn(dx, v0.x), __fmul_rn(dy, v0.y)), __fmul_rn(dz, v0.z));
    float t1 = __fadd_rn(__fadd_rn(__fmul_rn(dx, v1.x), __fmul_rn(dy, v1.y)), __fmul_rn(dz, v1.z));
    float t2 = __fadd_rn(__fadd_rn(__fmul_rn(dx, v2.x), __fmul_rn(dy, v2.y)), __fmul_rn(dz, v2.z));
    return __fadd_rn(__fadd_rn(__fmul_rn(t0, dx), __fmul_rn(t1, dy)), __fmul_rn(t2, dz));
}

// ---------- kernel 1: everything fused ----------
// R9 changes (output-bit-exact; pen reduction order was already nondeterministic
// under atomics and tolerance-checked):
//  * atomic convoy removed: 2048 same-address atomicAdds (all arriving in one
//    end-of-kernel convoy, serialized at one TCC channel ~8-17 us exposed)
//    replaced by per-wave slot stores ws[block*4+wave] -- plain coalesced
//    stores, no zeroing required (every slot written unconditionally), so
//    k_zero launch is gone too.
//  * 24-row register prefetch issued BEFORE the table build (after the small
//    loads + table-input loads, pinned by asm memory clobber). In-order vmem
//    retire => the compiler's wait for table inputs is a counted vmcnt(24),
//    not a drain; sincos table build overlaps the stream start.
// Order discipline:
//   1. wxyz/dists + centers/radii/rots loads   -- issued first (older)
//   2. 24x global_load_dwordx4 -> rpre[]       -- younger, stay in flight
//   3. table build (waits vmcnt(24): counted)  + ds_write (column-major float4)
//   4. lgkmcnt(0) + raw s_barrier              -- no forced vmcnt drain
//   5. pass-1 (VALU + ds_read only)            -- prefetch still in flight
//   6. pass-2: rpre rows 0..23 (counted vmcnt waits), stream rows 24..127
// Selection semantics unchanged: qcut = 16th-smallest q via med3 ladder
// (min(top[k],max(q,top[k-1])) == med3 under the ascending invariant);
// blend mask (q <= qcut) && (w >= 0.01); pen guard q <= 13 exact
// (w(13)=0.0075 < 0.01). Masked rows contribute exact +0.0 to all sums.
__global__ __launch_bounds__(256, 2) void k_main(
        const float* __restrict__ wxyz,
        const float* __restrict__ centers,
        const float* __restrict__ radii,
        const float* __restrict__ rots,
        const float* __restrict__ dists,
        const float4* __restrict__ rgbs,
        float4* __restrict__ outv,
        float* __restrict__ pen_slots) {
    __shared__ float4 sws4[NCEN * 3];         // 6144 B

    int tid = threadIdx.x;
    int p = blockIdx.x * 256 + tid;

    // ---- (1) small loads + table-input loads first (older in vmem queue) ----
    float px = wxyz[3 * p + 0];
    float py = wxyz[3 * p + 1];
    float pz = wxyz[3 * p + 2];
    float dist = dists[p];

    float c0 = 0.f, c1 = 0.f, c2 = 0.f;
    float rd0 = 0.f, rd1 = 0.f, rd2 = 0.f;
    float a0 = 0.f, a1 = 0.f, a2 = 0.f;
    if (tid < NCEN) {                         // waves 0,1 fully active
        c0 = centers[3 * tid + 0];
        c1 = centers[3 * tid + 1];
        c2 = centers[3 * tid + 2];
        rd0 = radii[3 * tid + 0];
        rd1 = radii[3 * tid + 1];
        rd2 = radii[3 * tid + 2];
        a0 = rots[3 * tid + 0];
        a1 = rots[3 * tid + 1];
        a2 = rots[3 * tid + 2];
    }
    asm volatile("" ::: "memory");            // pin: prefetch issues after these

    // ---- (2) register prefetch: 24 rows, in flight across table + pass-1 ----
    const float4* gsrc = rgbs + p;
    float4 rpre[RROWS];
#pragma unroll
    for (int r = 0; r < RROWS; ++r)
        rpre[r] = gsrc[(size_t)r * NPTS];

    // ---- (3) per-block inv_cov table (identical math to before) ----
    if (tid < NCEN) {
        float d0 = 1.0f / (fabsf(rd0) + 1e-8f);
        float d1 = 1.0f / (fabsf(rd1) + 1e-8f);
        float d2 = 1.0f / (fabsf(rd2) + 1e-8f);
        float cx = cosf(a0), cy = cosf(a1), cz = cosf(a2);
        float sx = sinf(a0), sy = sinf(a1), sz = sinf(a2);
        float R[9];
        R[0] = __fmul_rn(cz, cy);
        R[1] = __fsub_rn(__fmul_rn(__fmul_rn(cz, sy), sx), __fmul_rn(sz, cx));
        R[2] = __fadd_rn(__fmul_rn(__fmul_rn(cz, sy), cx), __fmul_rn(sz, sx));
        R[3] = __fmul_rn(sz, cy);
        R[4] = __fadd_rn(__fmul_rn(__fmul_rn(sz, sy), sx), __fmul_rn(cz, cx));
        R[5] = __fsub_rn(__fmul_rn(__fmul_rn(sz, sy), cx), __fmul_rn(cz, sx));
        R[6] = -sy;
        R[7] = __fmul_rn(cy, sx);
        R[8] = __fmul_rn(cy, cx);
        float T[9];
        T[0] = __fmul_rn(R[0], d0); T[1] = __fmul_rn(R[1], d1); T[2] = __fmul_rn(R[2], d2);
        T[3] = __fmul_rn(R[3], d0); T[4] = __fmul_rn(R[4], d1); T[5] = __fmul_rn(R[5], d2);
        T[6] = __fmul_rn(R[6], d0); T[7] = __fmul_rn(R[7], d1); T[8] = __fmul_rn(R[8], d2);
        float W[9];
#pragma unroll
        for (int a = 0; a < 3; ++a)
#pragma unroll
            for (int c = 0; c < 3; ++c)
                W[3 * a + c] = __fadd_rn(__fadd_rn(__fmul_rn(T[3 * a + 0], R[3 * c + 0]),
                                                   __fmul_rn(T[3 * a + 1], R[3 * c + 1])),
                                         __fmul_rn(T[3 * a + 2], R[3 * c + 2]));
        // column-major store: v_c = (W[0*3+c], W[1*3+c], W[2*3+c], center[c])
        sws4[tid * 3 + 0] = make_float4(W[0], W[3], W[6], c0);
        sws4[tid * 3 + 1] = make_float4(W[1], W[4], W[7], c1);
        sws4[tid * 3 + 2] = make_float4(W[2], W[5], W[8], c2);
    }
    // ---- (4) raw barrier: drain LDS writes only; prefetch stays in flight ----
    asm volatile("s_waitcnt lgkmcnt(0)" ::: "memory");
    __builtin_amdgcn_s_barrier();

    // ---- (5) pass 1: q over all 128 centers; pen (guarded, exact); top-16 ----
    float top[16];             // 16 smallest q, ascending
#pragma unroll
    for (int i = 0; i < 16; ++i) top[i] = 3.0e38f;
    float pen = 0.f;

    for (int n = 0; n < NCEN; ++n) {
        float4 v0 = sws4[n * 3 + 0];
        float4 v1 = sws4[n * 3 + 1];
        float4 v2 = sws4[n * 3 + 2];
        float q = qeval4(v0, v1, v2, px, py, pz);
        if (q <= 13.0f) {
            float wv = __fmul_rn(5.0f, expf(__fmul_rn(-0.5f, q)));
            pen = __fadd_rn(pen, fmaxf(__fsub_rn(wv, 0.01f), 0.f));
        }
#pragma unroll
        for (int k = 15; k >= 1; --k)
            top[k] = __builtin_amdgcn_fmed3f(q, top[k - 1], top[k]);
        top[0] = fminf(top[0], q);
    }
    float qcut = top[15];

    // ---- (6) pass 2: rpre rows 0..23 (counted waits), stream rows 24..127 ----
    float wsum = 0.f, s0 = 0.f, s1 = 0.f, s2 = 0.f, s3 = 0.f;
#define ACCUM(nn, rv) do {                                                        \
        float4 u0 = sws4[(nn) * 3 + 0];                                           \
        float4 u1 = sws4[(nn) * 3 + 1];                                           \
        float4 u2 = sws4[(nn) * 3 + 2];                                           \
        float q = qeval4(u0, u1, u2, px, py, pz);                                 \
        float wv = __fmul_rn(5.0f, expf(__fmul_rn(-0.5f, q)));                    \
        float mw = ((q <= qcut) && (wv >= 0.01f)) ? wv : 0.0f;                    \
        float al = __fsub_rn(1.0f, expf(-__fmul_rn(fmaxf((rv).w, 0.f), dist)));   \
        wsum += mw;                                                               \
        s0 = __fmaf_rn(mw, (rv).x, s0);                                           \
        s1 = __fmaf_rn(mw, (rv).y, s1);                                           \
        s2 = __fmaf_rn(mw, (rv).z, s2);                                           \
        s3 = __fmaf_rn(mw, al, s3);                                               \
    } while (0)

#pragma unroll
    for (int n = 0; n < RROWS; ++n) {
        ACCUM(n, rpre[n]);
    }
#pragma unroll 8
    for (int n = RROWS; n < NCEN; ++n) {
        float4 rv = rgbs[(size_t)n * NPTS + p];
        ACCUM(n, rv);
    }
#undef ACCUM

    float inv = 1.0f / (wsum + 1e-7f);
    float4 o;
    o.x = s0 * inv; o.y = s1 * inv; o.z = s2 * inv; o.w = s3 * inv;
    outv[p] = o;               // 16B/lane, fully coalesced

    // penalty: wave shuffle reduce, then ONE PLAIN STORE per wave to its own
    // slot (no atomic, no pre-zeroing -- every slot written unconditionally)
    float v = pen;
#pragma unroll
    for (int off = 32; off > 0; off >>= 1) v += __shfl_down(v, off);
    if ((tid & 63) == 0)
        pen_slots[blockIdx.x * 4 + (tid >> 6)] = v;
}

// ---------- kernel 2: reduce 2048 pen slots + bbox penalty, write scalar ----------
__global__ void k_finalize(const float* __restrict__ centers,
                           const float* __restrict__ slots,
                           float* __restrict__ out) {
    __shared__ float red[8];                  // 4 waves x {pen, bb}
    int t = threadIdx.x;                      // 256 threads
    float pen = 0.f;
#pragma unroll
    for (int i = 0; i < NBLK * 4 / 256; ++i)  // 8 strided loads each
        pen += slots[t + 256 * i];
    float bb = 0.f;
    if (t < NCEN) {
        float c0 = centers[3 * t + 0];
        float c1 = centers[3 * t + 1];
        float c2 = centers[3 * t + 2];
        bb = fmaxf(c0 - 0.5f, 0.f) + fmaxf(-0.5f - c0, 0.f)
           + fmaxf(c1 - 0.5f, 0.f) + fmaxf(-0.5f - c1, 0.f)
           + fmaxf(c2 - 0.5f, 0.f) + fmaxf(-0.5f - c2, 0.f);
    }
#pragma unroll
    for (int off = 32; off > 0; off >>= 1) {
        pen += __shfl_down(pen, off);
        bb  += __shfl_down(bb, off);
    }
    if ((t & 63) == 0) {
        red[(t >> 6) * 2 + 0] = pen;
        red[(t >> 6) * 2 + 1] = bb;
    }
    __syncthreads();
    if (t == 0) {
        float pt = red[0] + red[2] + red[4] + red[6];
        float bt = red[1] + red[3] + red[5] + red[7];
        float m = pt / (float)NPTS;           // mean over points
        out[NPTS * 4] = __fadd_rn(__fmul_rn(0.001f, m), bt);
    }
}

extern "C" void kernel_launch(void* const* d_in, const int* in_sizes, int n_in,
                              void* d_out, int out_size, void* d_ws, size_t ws_size,
                              hipStream_t stream) {
    const float*  wxyz  = (const float*)d_in[0];
    const float*  cen   = (const float*)d_in[1];
    const float*  rad   = (const float*)d_in[2];
    const float*  rot   = (const float*)d_in[3];
    const float4* rgbs  = (const float4*)d_in[4];
    const float*  dists = (const float*)d_in[5];
    float* ws = (float*)d_ws;

    hipLaunchKernelGGL(k_main, dim3(NBLK), dim3(256), 0, stream,
                       wxyz, cen, rad, rot, dists, rgbs, (float4*)d_out, ws);
    hipLaunchKernelGGL(k_finalize, dim3(1), dim3(256), 0, stream, cen, ws, (float*)d_out);
}